// Round 2
// baseline (322.794 us; speedup 1.0000x reference)
//
#include <hip/hip_runtime.h>

typedef short short8 __attribute__((ext_vector_type(8)));
typedef float floatx4 __attribute__((ext_vector_type(4)));

__device__ __forceinline__ unsigned short f2bf(float f) {
  unsigned u = __float_as_uint(f);
  u += 0x7FFFu + ((u >> 16) & 1u);   // round-to-nearest-even
  return (unsigned short)(u >> 16);
}

// ---------------------------------------------------------------------------
// Kernel 1a: partial projections. part[(which*8+dchunk)*512 + n][c] = sum over
// 256 d of im[n][d] * W[d][c].
// Re-tiled for occupancy: grid (8 dchunks, 32 rowtiles, 2 which) x 512 thr
// = 4096 waves (4/SIMD) vs previous 1024 (1/SIMD).  Each thread: 1 row x 4 col.
// ---------------------------------------------------------------------------
__global__ __launch_bounds__(512, 4) void proj_partial(
    const float* __restrict__ im_q, const float* __restrict__ im_k,
    const float* __restrict__ Wq, const float* __restrict__ Wk,
    float* __restrict__ part, int* __restrict__ cnt) {
  __shared__ float imS[16 * 260];  // [r][d], stride 260 f32 (pad)
  const int t = threadIdx.x;
  if (blockIdx.x == 0 && blockIdx.y == 0 && blockIdx.z == 0 && t < 4) cnt[t] = 0;
  const int which = blockIdx.z;
  const float* __restrict__ im = which ? im_k : im_q;
  const float* __restrict__ W  = which ? Wk : Wq;
  const int d0 = blockIdx.x * 256;
  const int row0 = blockIdx.y * 16;
#pragma unroll
  for (int p = 0; p < 2; ++p) {
    const int idx = t + p * 512;         // 1024 float4 = 16 rows x 256 d
    const int r = idx >> 6;
    const int dd = (idx & 63) * 4;
    *(float4*)(imS + r * 260 + dd) =
        *(const float4*)(im + (size_t)(row0 + r) * 2048 + d0 + dd);
  }
  __syncthreads();
  const int c4 = (t & 31) * 4;   // 32 col groups * 4 = 128 cols
  const int r  = t >> 5;         // 16 rows
  float acc0 = 0.f, acc1 = 0.f, acc2 = 0.f, acc3 = 0.f;
  const float* __restrict__ Wp = W + (size_t)d0 * 128 + c4;
#pragma unroll 8
  for (int d = 0; d < 256; ++d) {
    const float4 w = *(const float4*)(Wp + (size_t)d * 128);   // L2-hot (reused x32)
    const float a = imS[r * 260 + d];                          // LDS broadcast
    acc0 += a * w.x; acc1 += a * w.y; acc2 += a * w.z; acc3 += a * w.w;
  }
  *(float4*)(part + ((size_t)(which * 8 + blockIdx.x) * 512 + row0 + r) * 128 + c4) =
      make_float4(acc0, acc1, acc2, acc3);
}

// ---------------------------------------------------------------------------
// Kernel 1b: reduce partials, normalize, l_pos, q->bf16, group lists, labels=0
// grid 512 blocks x 128 threads (one block per sample n)
// ---------------------------------------------------------------------------
__global__ __launch_bounds__(128) void finalize(
    const float* __restrict__ part, const int* __restrict__ label,
    unsigned short* __restrict__ qbf, int* __restrict__ cnt,
    int* __restrict__ rows, float* __restrict__ out) {
  const int n = blockIdx.x, c = threadIdx.x;
  float qraw = 0.f, kraw = 0.f;
#pragma unroll
  for (int ch = 0; ch < 8; ++ch) {
    qraw += part[((size_t)ch * 512 + n) * 128 + c];
    kraw += part[((size_t)(8 + ch) * 512 + n) * 128 + c];
  }
  float sq = qraw * qraw, sk = kraw * kraw, dt = qraw * kraw;
#pragma unroll
  for (int off = 32; off > 0; off >>= 1) {
    sq += __shfl_down(sq, off, 64);
    sk += __shfl_down(sk, off, 64);
    dt += __shfl_down(dt, off, 64);
  }
  __shared__ float sh[3][2];
  const int lane = c & 63, wv = c >> 6;
  if (lane == 0) { sh[0][wv] = sq; sh[1][wv] = sk; sh[2][wv] = dt; }
  __syncthreads();
  const float tsq = sh[0][0] + sh[0][1];
  const float tsk = sh[1][0] + sh[1][1];
  const float tdt = sh[2][0] + sh[2][1];
  const float nq = fmaxf(sqrtf(tsq), 1e-12f);
  const float nk = fmaxf(sqrtf(tsk), 1e-12f);
  qbf[n * 128 + c] = f2bf(qraw / nq);
  if (c == 0) {
    out[(size_t)n * 65537] = tdt / (nq * nk) * (1.0f / 0.07f);   // l_pos / T
    ((int*)out)[(size_t)512 * 65537 + n] = 0;                    // labels
    int g = ((label[n] - 1) % 4 + 4) % 4;                        // (label-1) mod 4
    int pos = atomicAdd(cnt + g, 1);
    rows[g * 512 + pos] = n;
  }
}

// ---------------------------------------------------------------------------
// Kernel 1c: pack A-fragments in exact MFMA order so moco_lneg needs no Q LDS.
// Apack[(g*4+ch)*2048 + kk*512 + rb*64 + lane][e] =
//   Q[chunk row rb*16+(lane&15)][kk*32+(lane>>4)*8+e]   (zero-padded)
// grid 16 blocks (g,ch) x 256 thr.  512 KB total, aliases dead `part` buffer.
// ---------------------------------------------------------------------------
__global__ __launch_bounds__(256) void qpack(
    const unsigned short* __restrict__ qbf, const int* __restrict__ cnt,
    const int* __restrict__ rows, unsigned short* __restrict__ Apack) {
  const int g = blockIdx.x >> 2, ch = blockIdx.x & 3;
  const int Mg = cnt[g];
  const int t = threadIdx.x;
#pragma unroll
  for (int w = 0; w < 8; ++w) {
    const int slot = w * 256 + t;               // 0..2047
    const int kk = slot >> 9;
    const int rb = (slot >> 6) & 7;
    const int lane = slot & 63;
    const int l16 = lane & 15, qd = lane >> 4;
    const int m = ch * 128 + rb * 16 + l16;
    uint4 v = make_uint4(0u, 0u, 0u, 0u);
    if (m < Mg) {
      const int n = rows[g * 512 + m];
      v = *(const uint4*)(qbf + (size_t)n * 128 + kk * 32 + qd * 8);
    }
    *(uint4*)(Apack + ((size_t)blockIdx.x * 2048 + slot) * 8) = v;
  }
}

// ---------------------------------------------------------------------------
// Kernel 2: grouped GEMM l_neg = Q_g @ queues[g], bf16 MFMA, /T on epilogue.
// grid (512 col tiles, 4 groups) x 256 threads.
// Bs stride 136 ushorts (272 B = 17*16 B): 16B-aligned ds_read_b128 fragments
// with ~2-way banks (odd 17 factor), conflict-free u32 staging writes.
// A-fragments stream from Apack (global, L2-hot, same addr across waves).
// LDS ~37 KB -> 4 blocks/CU; exactly ONE barrier per block.
// ---------------------------------------------------------------------------
__global__ __launch_bounds__(256, 4) void moco_lneg(
    const float* __restrict__ queues, const unsigned short* __restrict__ Apack,
    const int* __restrict__ cnt, const int* __restrict__ rows,
    float* __restrict__ out) {
  __shared__ __align__(16) unsigned short Bs[128 * 136];  // [j][c] bf16
  __shared__ int rowsS[512];
  const int g = blockIdx.y;
  const int Mg = cnt[g];
  if (Mg == 0) return;
  const int t = threadIdx.x;
  const int j0 = blockIdx.x * 128;
  // ---- stage B tile (fp32 global -> bf16 LDS, transposed) ----
  {
    const int j = t & 127;
    const int cb = (t >> 7) * 64;
    const float* __restrict__ qb = queues + (size_t)g * 128 * 65536 + j0 + j;
#pragma unroll 8
    for (int p = 0; p < 32; ++p) {
      const int c = cb + p * 2;
      const float f0 = qb[(size_t)c * 65536];
      const float f1 = qb[(size_t)(c + 1) * 65536];
      const unsigned u = (unsigned)f2bf(f0) | ((unsigned)f2bf(f1) << 16);
      *(unsigned*)(Bs + j * 136 + c) = u;   // bank = (17j + c/2) % 32: bijective
    }
  }
  for (int i = t; i < 512; i += 256) rowsS[i] = rows[g * 512 + i];
  __syncthreads();   // the only barrier: Bs/rowsS are read-only afterwards
  const int lane = t & 63, wave = t >> 6;
  const int qd = lane >> 4, l16 = lane & 15;
  const float invT = 1.0f / 0.07f;
  const int nch = (Mg + 127) >> 7;
  const unsigned short* __restrict__ Ag = Apack + (size_t)g * 4 * 16384 + lane * 8;
  for (int ch = 0; ch < nch; ++ch) {
    const int valid = min(Mg - ch * 128, 128);
    const unsigned short* __restrict__ Ab = Ag + (size_t)ch * 16384;
    floatx4 acc[8][2];
#pragma unroll
    for (int rb = 0; rb < 8; ++rb) {
      floatx4 z = {0.f, 0.f, 0.f, 0.f};
      acc[rb][0] = z; acc[rb][1] = z;
    }
    __builtin_amdgcn_s_setprio(1);
#pragma unroll
    for (int kk = 0; kk < 4; ++kk) {
      const int k0 = kk * 32 + qd * 8;
      const short8 bfrag0 = *(const short8*)&Bs[((wave * 2 + 0) * 16 + l16) * 136 + k0];
      const short8 bfrag1 = *(const short8*)&Bs[((wave * 2 + 1) * 16 + l16) * 136 + k0];
#pragma unroll
      for (int rb = 0; rb < 8; ++rb) {
        if (rb * 16 < valid) {   // wave-uniform: near-empty tail chunk skips work
          const short8 afrag = *(const short8*)(Ab + kk * 4096 + rb * 512);
          acc[rb][0] = __builtin_amdgcn_mfma_f32_16x16x32_bf16(afrag, bfrag0, acc[rb][0], 0, 0, 0);
          acc[rb][1] = __builtin_amdgcn_mfma_f32_16x16x32_bf16(afrag, bfrag1, acc[rb][1], 0, 0, 0);
        }
      }
    }
    __builtin_amdgcn_s_setprio(0);
    // ---- epilogue: C/D layout col=lane&15, row=quad*4+reg ----
#pragma unroll
    for (int rb = 0; rb < 8; ++rb) {
      if (rb * 16 < valid) {
#pragma unroll
        for (int r = 0; r < 4; ++r) {
          const int ml = rb * 16 + qd * 4 + r;
          if (ml < valid) {
            const size_t base = (size_t)rowsS[ch * 128 + ml] * 65537 + 1 + j0;
            out[base + (wave * 2 + 0) * 16 + l16] = acc[rb][0][r] * invT;
            out[base + (wave * 2 + 1) * 16 + l16] = acc[rb][1][r] * invT;
          }
        }
      }
    }
  }
}

extern "C" void kernel_launch(void* const* d_in, const int* in_sizes, int n_in,
                              void* d_out, int out_size, void* d_ws, size_t ws_size,
                              hipStream_t stream) {
  const float* im_q   = (const float*)d_in[0];
  const float* im_k   = (const float*)d_in[1];
  const float* Wq     = (const float*)d_in[2];
  const float* Wk     = (const float*)d_in[3];
  const float* queues = (const float*)d_in[4];
  const int*   label  = (const int*)d_in[5];
  float* out = (float*)d_out;

  char* ws = (char*)d_ws;
  float* part = (float*)ws;                                   // 2*8*512*128 f32 = 4 MB
  unsigned short* qbf = (unsigned short*)(ws + (4u << 20));   // 512*128 bf16 = 128 KB
  int* cnt  = (int*)(ws + (4u << 20) + (128u << 10));         // 4 ints
  int* rows = cnt + 4;                                        // 4*512 ints
  // Apack aliases `part` (dead after finalize; qpack runs after finalize).
  unsigned short* Apack = (unsigned short*)ws;                // 16*2048*8 bf16 = 512 KB

  proj_partial<<<dim3(8, 32, 2), 512, 0, stream>>>(im_q, im_k, Wq, Wk, part, cnt);
  finalize<<<512, 128, 0, stream>>>(part, label, qbf, cnt, rows, out);
  qpack<<<16, 256, 0, stream>>>(qbf, cnt, rows, Apack);
  moco_lneg<<<dim3(512, 4), 256, 0, stream>>>(queues, Apack, cnt, rows, out);
}